// Round 1
// 1627.845 us; speedup vs baseline: 1.0470x; 1.0470x over previous
//
#include <hip/hip_runtime.h>
#include <math.h>

#define LQ 2048
#define DMODEL 3072
#define NHEADS 24
#define DHEADC 128
#define NQKV 9216
#define NOUT1 21504
#define KIN2 15360
#define EPSV 1e-6f

typedef __attribute__((ext_vector_type(8))) short short8;
typedef __attribute__((ext_vector_type(4))) short short4v;
typedef __attribute__((ext_vector_type(4))) float f32x4;

__device__ __forceinline__ short f2bf(float f) {
  unsigned int u = __float_as_uint(f);
  unsigned int r = (u + 0x7fffu + ((u >> 16) & 1u)) >> 16;
  return (short)(unsigned short)r;
}

__device__ __forceinline__ float geluf(float v) {
  float inner = 0.7978845608028654f * (v + 0.044715f * v * v * v);
  return 0.5f * v * (1.0f + tanhf(inner));
}

// async global->LDS DMA, 16 B per lane; LDS dst = base + lane*16 (wave-uniform base)
__device__ __forceinline__ void async_ld16(void* lds, const void* g) {
  __builtin_amdgcn_global_load_lds(
      (const __attribute__((address_space(1))) unsigned int*)g,
      (__attribute__((address_space(3))) unsigned int*)lds, 16, 0, 0);
}

// ---------------- fp32 (K,N) -> bf16 (N,K) transpose+convert ----------------
__global__ __launch_bounds__(256) void k_wconv(const float* __restrict__ w,
                                               short* __restrict__ wt,
                                               int K, int N) {
  __shared__ float tile[32][33];
  int bk = blockIdx.x * 32, bn = blockIdx.y * 32;
  int t = threadIdx.x;
  int r = t >> 3, c = (t & 7) * 4;
  float4 v = *reinterpret_cast<const float4*>(w + (size_t)(bk + r) * N + bn + c);
  tile[r][c + 0] = v.x; tile[r][c + 1] = v.y; tile[r][c + 2] = v.z; tile[r][c + 3] = v.w;
  __syncthreads();
  short4v o;
  o[0] = f2bf(tile[c + 0][r]); o[1] = f2bf(tile[c + 1][r]);
  o[2] = f2bf(tile[c + 2][r]); o[3] = f2bf(tile[c + 3][r]);
  *reinterpret_cast<short4v*>(wt + (size_t)(bn + r) * K + bk + c) = o;
}

// ---------------- mod = silu(vec) @ mod_w  (split-K GEMV) ----------------
__global__ __launch_bounds__(256) void k_modpart(const float* __restrict__ vec,
                                                 const float* __restrict__ mod_w,
                                                 float* __restrict__ partial) {
  __shared__ float sv[128];
  int t = threadIdx.x;
  int nb = blockIdx.x * 256;
  int kb = blockIdx.y * 128;
  if (t < 128) { float z = vec[kb + t]; sv[t] = z / (1.0f + expf(-z)); }
  __syncthreads();
  const float* wp = mod_w + (size_t)kb * NQKV + nb + t;
  float acc = 0.0f;
#pragma unroll 8
  for (int k = 0; k < 128; k++) acc += sv[k] * wp[(size_t)k * NQKV];
  partial[(size_t)blockIdx.y * NQKV + nb + t] = acc;
}

__global__ __launch_bounds__(256) void k_modred(const float* __restrict__ partial,
                                                const float* __restrict__ mod_b,
                                                float* __restrict__ modv) {
  int n = blockIdx.x * 256 + threadIdx.x;
  float acc = mod_b[n];
#pragma unroll
  for (int ky = 0; ky < 24; ky++) acc += partial[(size_t)ky * NQKV + n];
  modv[n] = acc;
}

// ---------------- LayerNorm + (1+scale)*xn + shift -> bf16 ----------------
__global__ __launch_bounds__(256) void k_ln(const float* __restrict__ x,
                                            const float* __restrict__ modv,
                                            short* __restrict__ xmod) {
  int l = blockIdx.x, t = threadIdx.x;
  const float* xr = x + (size_t)l * DMODEL;
  const float4* xr4 = (const float4*)xr;
  float4 vbuf[3];
  float s = 0.f, ss = 0.f;
#pragma unroll
  for (int i = 0; i < 3; i++) {
    float4 v = xr4[t + i * 256];
    vbuf[i] = v;
    s += v.x + v.y + v.z + v.w;
    ss += v.x * v.x + v.y * v.y + v.z * v.z + v.w * v.w;
  }
#pragma unroll
  for (int m = 32; m >= 1; m >>= 1) { s += __shfl_xor(s, m); ss += __shfl_xor(ss, m); }
  __shared__ float red[8];
  __shared__ float stats[2];
  int wave = t >> 6;
  if ((t & 63) == 0) { red[wave] = s; red[4 + wave] = ss; }
  __syncthreads();
  if (t == 0) {
    float st = red[0] + red[1] + red[2] + red[3];
    float sst = red[4] + red[5] + red[6] + red[7];
    float mu = st / DMODEL;
    float var = sst / DMODEL - mu * mu;
    stats[0] = mu; stats[1] = rsqrtf(var + EPSV);
  }
  __syncthreads();
  float mu = stats[0], rr = stats[1];
#pragma unroll
  for (int i = 0; i < 3; i++) {
    float4 v = vbuf[i];
    int c = (t + i * 256) * 4;
    short4v o;
    o[0] = f2bf((1.f + modv[DMODEL + c + 0]) * ((v.x - mu) * rr) + modv[c + 0]);
    o[1] = f2bf((1.f + modv[DMODEL + c + 1]) * ((v.y - mu) * rr) + modv[c + 1]);
    o[2] = f2bf((1.f + modv[DMODEL + c + 2]) * ((v.z - mu) * rr) + modv[c + 2]);
    o[3] = f2bf((1.f + modv[DMODEL + c + 3]) * ((v.w - mu) * rr) + modv[c + 3]);
    *(short4v*)(xmod + (size_t)l * DMODEL + c) = o;
  }
}

// ---------------- GEMM1: 256x256 tile, BK=64, 8-wave 8-phase counted-vmcnt ----------------
// T1 (XCD swizzle) + T2 (LDS XOR swizzle, linear dst + pre-swizzled global src)
// + T3/T4 (8-phase, vmcnt(6) only at phases 4/8) + T5 (setprio around MFMA).
// Quadrant order (mh,nh): (0,0)(0,1)(1,1)(1,0); LDS half-tile retirement:
// A0@ph1, B1@ph2, A1@ph3, B0@ph4 -> prefetch issue 1 half-tile/phase, 3 in flight.
#define G1_NT 48    // 3072 / 64
#define G1_NITER 24 // 2 K-tiles per iteration

__device__ __forceinline__ void ldA4(short8 af[4][2], const short* ldsA, int rbase,
                                     int lrow, const int* kOff) {
#pragma unroll
  for (int m = 0; m < 4; m++)
#pragma unroll
    for (int ks = 0; ks < 2; ks++)
      af[m][ks] = *(const short8*)&ldsA[(rbase + m * 16 + lrow) * 64 + kOff[ks]];
}

__device__ __forceinline__ void ldB2(short8 bfr[2][2], const short* ldsB, int rbase,
                                     int lrow, const int* kOff) {
#pragma unroll
  for (int n = 0; n < 2; n++)
#pragma unroll
    for (int ks = 0; ks < 2; ks++)
      bfr[n][ks] = *(const short8*)&ldsB[(rbase + n * 16 + lrow) * 64 + kOff[ks]];
}

// A half-tile (mh): rows mh*64 + {0..63} and 128+mh*64 + {0..63}; 16 chunks of 8 rows.
__device__ __forceinline__ void stage_halfA(short* ldsT, const short* G, int rowbase,
                                            int tauB, int half, int wid, int srow, int sk) {
#pragma unroll
  for (int c = 0; c < 2; c++) {
    int j = c * 8 + wid;
    int row0 = ((j >> 3) << 7) + half * 64 + ((j & 7) << 3);
    const char* src = (const char*)G +
                      (size_t)(rowbase + row0 + srow) * (size_t)(DMODEL * 2) + tauB + sk;
    async_ld16(ldsT + row0 * 64, src);
  }
}

// B half-tile (nh): rows wq*64 + nh*32 + {0..31} for wq=0..3; 16 chunks of 8 rows.
__device__ __forceinline__ void stage_halfB(short* ldsT, const short* G, int rowbase,
                                            int tauB, int half, int wid, int srow, int sk) {
#pragma unroll
  for (int c = 0; c < 2; c++) {
    int j = c * 8 + wid;
    int row0 = ((j >> 2) << 6) + half * 32 + ((j & 3) << 3);
    const char* src = (const char*)G +
                      (size_t)(rowbase + row0 + srow) * (size_t)(DMODEL * 2) + tauB + sk;
    async_ld16(ldsT + row0 * 64, src);
  }
}

#define SYNC_MFMA(mh, nh, VM)                                                       \
  do {                                                                              \
    if (VM) asm volatile("s_waitcnt vmcnt(6)" ::: "memory");                        \
    __builtin_amdgcn_s_barrier();                                                   \
    asm volatile("s_waitcnt lgkmcnt(0)" ::: "memory");                              \
    __builtin_amdgcn_sched_barrier(0);                                              \
    __builtin_amdgcn_s_setprio(1);                                                  \
    _Pragma("unroll") for (int m_ = 0; m_ < 4; m_++)                                \
      _Pragma("unroll") for (int n_ = 0; n_ < 2; n_++)                              \
        _Pragma("unroll") for (int k_ = 0; k_ < 2; k_++)                            \
          acc[(mh) * 4 + m_][(nh) * 2 + n_] =                                       \
              __builtin_amdgcn_mfma_f32_16x16x32_bf16(                              \
                  af[m_][k_], bfr[n_][k_], acc[(mh) * 4 + m_][(nh) * 2 + n_], 0, 0, 0); \
    __builtin_amdgcn_s_setprio(0);                                                  \
    __builtin_amdgcn_s_barrier();                                                   \
  } while (0)

#define G1_TB(tt) ((((tt) < G1_NT) ? (tt) : (G1_NT - 1)) * 128)

__global__ __launch_bounds__(512, 2) void k_gemm1_8p(const short* __restrict__ A,
                                                     const short* __restrict__ Bt,
                                                     const float* __restrict__ bias,
                                                     float* __restrict__ qraw,
                                                     float* __restrict__ kraw,
                                                     short* __restrict__ vt,
                                                     short* __restrict__ a2) {
  __shared__ __align__(16) short lds[2][2][256 * 64];  // [buf][A/B][row*64] = 128 KiB
  int t = threadIdx.x;
  int wid = t >> 6, lane = t & 63;
  // T1: XCD-chunked bijective swizzle (672 % 8 == 0, 84 blocks/XCD chunk)
  int bid = blockIdx.x;
  int swzb = (bid & 7) * 84 + (bid >> 3);
  int bm = (swzb & 7) << 8;   // 8 M-tiles
  int bn = (swzb >> 3) << 8;  // 84 N-tiles
  int wm_ = (wid >> 2) << 7;  // 0 / 128
  int wn_ = (wid & 3) << 6;   // 0 / 64 / 128 / 192
  int lrow = lane & 15;
  int swzx = (lane & 7) << 4;  // byte XOR for frag reads (row&7 == lane&7 at all frag rows)
  int kOff[2];
#pragma unroll
  for (int ks = 0; ks < 2; ks++) kOff[ks] = ((ks * 64 + (lane >> 4) * 16) ^ swzx) >> 1;
  int srow = lane >> 3;                         // staging row within 8-row wave chunk
  int sk = ((lane & 7) * 16) ^ (srow << 4);     // pre-swizzled global chunk offset

  short* A0p = &lds[0][0][0];
  short* B0p = &lds[0][1][0];
  short* A1p = &lds[1][0][0];
  short* B1p = &lds[1][1][0];

  f32x4 zero = {0.f, 0.f, 0.f, 0.f};
  f32x4 acc[8][4];
#pragma unroll
  for (int i = 0; i < 8; i++)
#pragma unroll
    for (int j = 0; j < 4; j++) acc[i][j] = zero;
  short8 af[4][2], bfr[2][2];

  // prologue: tile0 (4 half-tiles) + tile1 {A0, B1, A1}; vmcnt(6) ensures tile0 resident
  stage_halfA(A0p, A, bm, 0, 0, wid, srow, sk);
  stage_halfA(A0p, A, bm, 0, 1, wid, srow, sk);
  stage_halfB(B0p, Bt, bn, 0, 0, wid, srow, sk);
  stage_halfB(B0p, Bt, bn, 0, 1, wid, srow, sk);
  stage_halfA(A1p, A, bm, 128, 0, wid, srow, sk);
  stage_halfB(B1p, Bt, bn, 128, 1, wid, srow, sk);
  stage_halfA(A1p, A, bm, 128, 1, wid, srow, sk);
  asm volatile("s_waitcnt vmcnt(6)" ::: "memory");
  __builtin_amdgcn_s_barrier();

#pragma unroll 1
  for (int it = 0; it < G1_NITER; ++it) {
    int T = it * 2;
    // ---- phases 1-4: compute tile T (buf0) ----
    // ph1 (0,0): read A0,B0; stage B0(T+1)->buf1
    ldA4(af, A0p, wm_, lrow, kOff);
    ldB2(bfr, B0p, wn_, lrow, kOff);
    stage_halfB(B1p, Bt, bn, G1_TB(T + 1), 0, wid, srow, sk);
    SYNC_MFMA(0, 0, 0);
    // ph2 (0,1): read B1; stage A0(T+2)->buf0 (A0 retired @ph1)
    ldB2(bfr, B0p, wn_ + 32, lrow, kOff);
    stage_halfA(A0p, A, bm, G1_TB(T + 2), 0, wid, srow, sk);
    SYNC_MFMA(0, 1, 0);
    // ph3 (1,1): read A1; stage B1(T+2)->buf0 (B1 retired @ph2)
    ldA4(af, A0p, wm_ + 64, lrow, kOff);
    stage_halfB(B0p, Bt, bn, G1_TB(T + 2), 1, wid, srow, sk);
    SYNC_MFMA(1, 1, 0);
    // ph4 (1,0): re-read B0; stage A1(T+2)->buf0 (A1 retired @ph3); vmcnt(6) -> tile T+1 resident
    ldB2(bfr, B0p, wn_, lrow, kOff);
    stage_halfA(A0p, A, bm, G1_TB(T + 2), 1, wid, srow, sk);
    SYNC_MFMA(1, 0, 1);
    // ---- phases 5-8: compute tile T+1 (buf1) ----
    // ph5 (0,0): stage B0(T+2)->buf0 (B0 retired @ph4)
    ldA4(af, A1p, wm_, lrow, kOff);
    ldB2(bfr, B1p, wn_, lrow, kOff);
    stage_halfB(B0p, Bt, bn, G1_TB(T + 2), 0, wid, srow, sk);
    SYNC_MFMA(0, 0, 0);
    // ph6 (0,1): stage A0(T+3)->buf1
    ldB2(bfr, B1p, wn_ + 32, lrow, kOff);
    stage_halfA(A1p, A, bm, G1_TB(T + 3), 0, wid, srow, sk);
    SYNC_MFMA(0, 1, 0);
    // ph7 (1,1): stage B1(T+3)->buf1
    ldA4(af, A1p, wm_ + 64, lrow, kOff);
    stage_halfB(B1p, Bt, bn, G1_TB(T + 3), 1, wid, srow, sk);
    SYNC_MFMA(1, 1, 0);
    // ph8 (1,0): stage A1(T+3)->buf1; vmcnt(6) -> tile T+2 resident
    ldB2(bfr, B1p, wn_, lrow, kOff);
    stage_halfA(A1p, A, bm, G1_TB(T + 3), 1, wid, srow, sk);
    SYNC_MFMA(1, 0, 1);
  }

  // epilogue: per-wave 128x64 C region; C/D layout col=lane&15, row=(lane>>4)*4+r
  int r0 = bm + wm_ + ((lane >> 4) << 2);
  int c0 = bn + wn_ + lrow;
#pragma unroll
  for (int an = 0; an < 4; an++) {
    int col = c0 + an * 16;
    float bb = bias[col];
#pragma unroll
    for (int am = 0; am < 8; am++) {
#pragma unroll
      for (int r = 0; r < 4; r++) {
        float v = acc[am][an][r] + bb;
        int row = r0 + am * 16 + r;
        if (col < NQKV) {
          int s = col / DMODEL;
          int rem = col - s * DMODEL;
          int hh = rem >> 7, d = rem & 127;
          if (s == 0)      qraw[((size_t)hh * LQ + row) * DHEADC + d] = v;
          else if (s == 1) kraw[((size_t)hh * LQ + row) * DHEADC + d] = v;
          else             vt[((size_t)hh * DHEADC + d) * LQ + row] = f2bf(v);
        } else {
          a2[(size_t)row * KIN2 + DMODEL + (col - NQKV)] = f2bf(geluf(v));
        }
      }
    }
  }
}

// ---------------- RMSnorm + RoPE for q,k -> bf16 [h][l][d] ----------------
__global__ __launch_bounds__(256) void k_qkprep(const float* __restrict__ qraw,
                                                const float* __restrict__ kraw,
                                                const float* __restrict__ pe,
                                                const float* __restrict__ q_scale,
                                                const float* __restrict__ k_scale,
                                                short* __restrict__ qn,
                                                short* __restrict__ kn) {
  int wave = threadIdx.x >> 6, lane = threadIdx.x & 63;
  int l = blockIdx.x * 4 + wave;
  int h = blockIdx.y;
  int isK = blockIdx.z;
  const float* src = (isK ? kraw : qraw) + ((size_t)h * LQ + l) * DHEADC;
  const float* sc  = isK ? k_scale : q_scale;
  short* dst = (isK ? kn : qn) + ((size_t)h * LQ + l) * DHEADC;
  float2 tv = *(const float2*)(src + lane * 2);
  float ssq = tv.x * tv.x + tv.y * tv.y;
#pragma unroll
  for (int m = 1; m < 64; m <<= 1) ssq += __shfl_xor(ssq, m);
  float rr = rsqrtf(ssq * (1.0f / 128.0f) + EPSV);
  float t0 = tv.x * rr * sc[lane * 2];
  float t1 = tv.y * rr * sc[lane * 2 + 1];
  float4 p4 = *(const float4*)(pe + ((size_t)l * 64 + lane) * 4);
  float o0 = p4.x * t0 + p4.y * t1;
  float o1 = p4.z * t0 + p4.w * t1;
  if (!isK) { o0 *= 0.08838834764831845f; o1 *= 0.08838834764831845f; }  // 1/sqrt(128)
  dst[lane * 2] = f2bf(o0);
  dst[lane * 2 + 1] = f2bf(o1);
}

// ---------------- Flash attention: block = (head, 128 q rows) ----------------
__global__ __launch_bounds__(256) void k_flash(const short* __restrict__ qn,
                                               const short* __restrict__ kn,
                                               const short* __restrict__ vt,
                                               short* __restrict__ a2) {
  __shared__ short Qs[128][136];
  __shared__ short Ks[32][136];
  __shared__ short Vs[128][40];
  __shared__ short Ps[4][32][40];
  int t = threadIdx.x;
  int qb = blockIdx.x * 128, h = blockIdx.y;
  int wave = t >> 6, lane = t & 63;
  int lrow = lane & 15, lko = (lane >> 4) * 8;
  int wm = wave * 32;
  const short* qbase = qn + ((size_t)h * LQ + qb) * DHEADC;
#pragma unroll
  for (int i = 0; i < 8; i++) {
    int idx = i * 256 + t;
    int row = idx >> 4, c = (idx & 15) * 8;
    *(short8*)&Qs[row][c] = *(const short8*)(qbase + (size_t)row * DHEADC + c);
  }
  f32x4 zero = {0.f, 0.f, 0.f, 0.f};
  f32x4 oacc[2][8];
#pragma unroll
  for (int i = 0; i < 2; i++)
#pragma unroll
    for (int j = 0; j < 8; j++) oacc[i][j] = zero;
  float mI[2][4], lI[2][4];
#pragma unroll
  for (int i = 0; i < 2; i++)
#pragma unroll
    for (int r = 0; r < 4; r++) { mI[i][r] = -1e30f; lI[i][r] = 0.f; }
  __syncthreads();
  for (int kt = 0; kt < 64; kt++) {
    int krow0 = kt * 32;
#pragma unroll
    for (int i = 0; i < 2; i++) {
      int idx = i * 256 + t;
      int row = idx >> 4, c = (idx & 15) * 8;
      *(short8*)&Ks[row][c] = *(const short8*)(kn + ((size_t)h * LQ + krow0 + row) * DHEADC + c);
    }
#pragma unroll
    for (int i = 0; i < 2; i++) {
      int idx = i * 256 + t;
      int d = idx >> 2, c = (idx & 3) * 8;
      *(short8*)&Vs[d][c] = *(const short8*)(vt + ((size_t)h * DHEADC + d) * LQ + krow0 + c);
    }
    __syncthreads();
    f32x4 sacc[2][2];
#pragma unroll
    for (int i = 0; i < 2; i++)
#pragma unroll
      for (int j = 0; j < 2; j++) sacc[i][j] = zero;
#pragma unroll
    for (int kk = 0; kk < 4; kk++) {
      short8 qa[2], kb[2];
#pragma unroll
      for (int i = 0; i < 2; i++) qa[i] = *(const short8*)&Qs[wm + i * 16 + lrow][kk * 32 + lko];
#pragma unroll
      for (int j = 0; j < 2; j++) kb[j] = *(const short8*)&Ks[j * 16 + lrow][kk * 32 + lko];
#pragma unroll
      for (int i = 0; i < 2; i++)
#pragma unroll
        for (int j = 0; j < 2; j++)
          sacc[i][j] = __builtin_amdgcn_mfma_f32_16x16x32_bf16(qa[i], kb[j], sacc[i][j], 0, 0, 0);
    }
    // online softmax (rows live in (lane>>4, reg); reduce across lane&15)
#pragma unroll
    for (int i = 0; i < 2; i++) {
      float al[4];
#pragma unroll
      for (int r = 0; r < 4; r++) {
        float mx = fmaxf(sacc[i][0][r], sacc[i][1][r]);
#pragma unroll
        for (int m = 1; m < 16; m <<= 1) mx = fmaxf(mx, __shfl_xor(mx, m));
        float mnew = fmaxf(mI[i][r], mx);
        float alpha = exp2f((mI[i][r] - mnew) * 1.4426950408889634f);
        float p0 = exp2f((sacc[i][0][r] - mnew) * 1.4426950408889634f);
        float p1 = exp2f((sacc[i][1][r] - mnew) * 1.4426950408889634f);
        sacc[i][0][r] = p0; sacc[i][1][r] = p1;
        float rs = p0 + p1;
#pragma unroll
        for (int m = 1; m < 16; m <<= 1) rs += __shfl_xor(rs, m);
        lI[i][r] = lI[i][r] * alpha + rs;
        mI[i][r] = mnew;
        al[r] = alpha;
      }
#pragma unroll
      for (int j = 0; j < 8; j++) {
        f32x4 o = oacc[i][j];
        o[0] *= al[0]; o[1] *= al[1]; o[2] *= al[2]; o[3] *= al[3];
        oacc[i][j] = o;
      }
      // P: C/D layout -> LDS (transpose to A-operand layout)
#pragma unroll
      for (int j = 0; j < 2; j++)
#pragma unroll
        for (int r = 0; r < 4; r++)
          Ps[wave][i * 16 + (lane >> 4) * 4 + r][j * 16 + lrow] = f2bf(sacc[i][j][r]);
    }
    short8 pa[2];
#pragma unroll
    for (int i = 0; i < 2; i++) pa[i] = *(const short8*)&Ps[wave][i * 16 + lrow][lko];
#pragma unroll
    for (int j = 0; j < 8; j++) {
      short8 vb = *(const short8*)&Vs[j * 16 + lrow][lko];
#pragma unroll
      for (int i = 0; i < 2; i++)
        oacc[i][j] = __builtin_amdgcn_mfma_f32_16x16x32_bf16(pa[i], vb, oacc[i][j], 0, 0, 0);
    }
    __syncthreads();
  }
#pragma unroll
  for (int i = 0; i < 2; i++) {
    float inv[4];
#pragma unroll
    for (int r = 0; r < 4; r++) inv[r] = 1.0f / lI[i][r];
#pragma unroll
    for (int j = 0; j < 8; j++) {
#pragma unroll
      for (int r = 0; r < 4; r++) {
        int row = qb + wm + i * 16 + (lane >> 4) * 4 + r;
        int col = h * DHEADC + j * 16 + lrow;
        a2[(size_t)row * KIN2 + col] = f2bf(oacc[i][j][r] * inv[r]);
      }
    }
  }
}

// ---------------- GEMM2: a2(2048x15360) @ W2t(3072x15360)^T, fused residual ----------------
__global__ __launch_bounds__(256) void k_gemm2(const short* __restrict__ A,
                                               const short* __restrict__ Bt,
                                               const float* __restrict__ bias,
                                               const float* __restrict__ x,
                                               const float* __restrict__ gate,
                                               float* __restrict__ out) {
  __shared__ __align__(16) short As[128 * 32];
  __shared__ __align__(16) short Bs[128 * 32];
  const int K = KIN2;
  int t = threadIdx.x;
  int bm = blockIdx.x * 128, bn = blockIdx.y * 128;
  int wave = t >> 6, lane = t & 63;
  int wm = (wave >> 1) * 64, wn = (wave & 1) * 64;
  int lrow = lane & 15, lko = (lane >> 4) * 8;
  int srow = wave * 16 + (lane >> 2);
  int scol = (lane & 3) * 8;
  const short* ga0 = A + (size_t)(bm + srow) * K + scol;
  const short* ga1 = ga0 + (size_t)64 * K;
  const short* gb0 = Bt + (size_t)(bn + srow) * K + scol;
  const short* gb1 = gb0 + (size_t)64 * K;
  short* la0 = As + wave * 512;
  short* la1 = As + 64 * 32 + wave * 512;
  short* lb0 = Bs + wave * 512;
  short* lb1 = Bs + 64 * 32 + wave * 512;
  f32x4 zero = {0.f, 0.f, 0.f, 0.f};
  f32x4 acc[4][4];
#pragma unroll
  for (int i = 0; i < 4; i++)
#pragma unroll
    for (int j = 0; j < 4; j++) acc[i][j] = zero;
  for (int k0 = 0; k0 < K; k0 += 32) {
    __syncthreads();
    async_ld16(la0, ga0 + k0);
    async_ld16(la1, ga1 + k0);
    async_ld16(lb0, gb0 + k0);
    async_ld16(lb1, gb1 + k0);
    __syncthreads();
    short8 af[4], bfr[4];
#pragma unroll
    for (int i = 0; i < 4; i++) af[i] = *(const short8*)&As[(wm + i * 16 + lrow) * 32 + lko];
#pragma unroll
    for (int j = 0; j < 4; j++) bfr[j] = *(const short8*)&Bs[(wn + j * 16 + lrow) * 32 + lko];
#pragma unroll
    for (int i = 0; i < 4; i++)
#pragma unroll
      for (int j = 0; j < 4; j++)
        acc[i][j] = __builtin_amdgcn_mfma_f32_16x16x32_bf16(af[i], bfr[j], acc[i][j], 0, 0, 0);
  }
  int r0 = bm + wm + ((lane >> 4) << 2);
  int c0 = bn + wn + lrow;
#pragma unroll
  for (int j = 0; j < 4; j++) {
    int col = c0 + j * 16;
    float bb = bias[col];
    float g = gate[col];
#pragma unroll
    for (int i = 0; i < 4; i++) {
#pragma unroll
      for (int r = 0; r < 4; r++) {
        int row = r0 + i * 16 + r;
        float v = acc[i][j][r] + bb;
        out[(size_t)row * DMODEL + col] = x[(size_t)row * DMODEL + col] + g * v;
      }
    }
  }
}

extern "C" void kernel_launch(void* const* d_in, const int* in_sizes, int n_in,
                              void* d_out, int out_size, void* d_ws, size_t ws_size,
                              hipStream_t stream) {
  (void)in_sizes; (void)n_in; (void)out_size; (void)ws_size;
  const float* x       = (const float*)d_in[0];
  const float* vec     = (const float*)d_in[1];
  const float* pe      = (const float*)d_in[2];
  const float* mod_w   = (const float*)d_in[3];
  const float* mod_b   = (const float*)d_in[4];
  const float* lin1_w  = (const float*)d_in[5];
  const float* lin1_b  = (const float*)d_in[6];
  const float* lin2_w  = (const float*)d_in[7];
  const float* lin2_b  = (const float*)d_in[8];
  const float* q_scale = (const float*)d_in[9];
  const float* k_scale = (const float*)d_in[10];
  float* out = (float*)d_out;

  char* base = (char*)d_ws;
  size_t off = 0;
  auto carve = [&](size_t bytes) -> void* {
    void* q = base + off;
    off += (bytes + 255) & ~(size_t)255;
    return q;
  };
  short* W1t  = (short*)carve((size_t)NOUT1 * DMODEL * 2);      // also W2t later
  short* xmod = (short*)carve((size_t)LQ * DMODEL * 2);
  float* qraw = (float*)carve((size_t)NHEADS * LQ * DHEADC * 4);
  float* kraw = (float*)carve((size_t)NHEADS * LQ * DHEADC * 4);
  short* qnb  = (short*)carve((size_t)NHEADS * LQ * DHEADC * 2);
  short* knb  = (short*)carve((size_t)NHEADS * LQ * DHEADC * 2);
  short* vtb  = (short*)carve((size_t)NHEADS * LQ * DHEADC * 2);
  short* a2   = (short*)carve((size_t)LQ * KIN2 * 2);
  float* modv = (float*)carve((size_t)NQKV * 4);
  float* part = (float*)carve((size_t)24 * NQKV * 4);

  k_wconv<<<dim3(DMODEL / 32, NOUT1 / 32), 256, 0, stream>>>(lin1_w, W1t, DMODEL, NOUT1);
  k_modpart<<<dim3(NQKV / 256, 24), 256, 0, stream>>>(vec, mod_w, part);
  k_modred<<<NQKV / 256, 256, 0, stream>>>(part, mod_b, modv);
  k_ln<<<LQ, 256, 0, stream>>>(x, modv, xmod);
  k_gemm1_8p<<<dim3((LQ / 256) * (NOUT1 / 256)), 512, 0, stream>>>(xmod, W1t, lin1_b,
                                                                   qraw, kraw, vtb, a2);
  k_wconv<<<dim3(KIN2 / 32, DMODEL / 32), 256, 0, stream>>>(lin2_w, W1t, KIN2, DMODEL);
  k_qkprep<<<dim3(LQ / 4, NHEADS, 2), 256, 0, stream>>>(qraw, kraw, pe, q_scale, k_scale, qnb, knb);
  k_flash<<<dim3(LQ / 128, NHEADS), 256, 0, stream>>>(qnb, knb, vtb, a2);
  k_gemm2<<<dim3(LQ / 128, DMODEL / 128), 256, 0, stream>>>(a2, W1t, lin2_b, x, modv + 2 * DMODEL, out);
}

// Round 2
// 1476.463 us; speedup vs baseline: 1.1543x; 1.1025x over previous
//
#include <hip/hip_runtime.h>
#include <math.h>

#define LQ 2048
#define DMODEL 3072
#define NHEADS 24
#define DHEADC 128
#define NQKV 9216
#define NOUT1 21504
#define KIN2 15360
#define EPSV 1e-6f

typedef __attribute__((ext_vector_type(8))) short short8;
typedef __attribute__((ext_vector_type(4))) short short4v;
typedef __attribute__((ext_vector_type(4))) float f32x4;

__device__ __forceinline__ short f2bf(float f) {
  unsigned int u = __float_as_uint(f);
  unsigned int r = (u + 0x7fffu + ((u >> 16) & 1u)) >> 16;
  return (short)(unsigned short)r;
}

__device__ __forceinline__ float geluf(float v) {
  float inner = 0.7978845608028654f * (v + 0.044715f * v * v * v);
  return 0.5f * v * (1.0f + tanhf(inner));
}

// async global->LDS DMA, 16 B per lane; LDS dst = base + lane*16 (wave-uniform base)
__device__ __forceinline__ void async_ld16(void* lds, const void* g) {
  __builtin_amdgcn_global_load_lds(
      (const __attribute__((address_space(1))) unsigned int*)g,
      (__attribute__((address_space(3))) unsigned int*)lds, 16, 0, 0);
}

// ---------------- fp32 (K,N) -> bf16 (N,K) transpose+convert ----------------
__global__ __launch_bounds__(256) void k_wconv(const float* __restrict__ w,
                                               short* __restrict__ wt,
                                               int K, int N) {
  __shared__ float tile[32][33];
  int bk = blockIdx.x * 32, bn = blockIdx.y * 32;
  int t = threadIdx.x;
  int r = t >> 3, c = (t & 7) * 4;
  float4 v = *reinterpret_cast<const float4*>(w + (size_t)(bk + r) * N + bn + c);
  tile[r][c + 0] = v.x; tile[r][c + 1] = v.y; tile[r][c + 2] = v.z; tile[r][c + 3] = v.w;
  __syncthreads();
  short4v o;
  o[0] = f2bf(tile[c + 0][r]); o[1] = f2bf(tile[c + 1][r]);
  o[2] = f2bf(tile[c + 2][r]); o[3] = f2bf(tile[c + 3][r]);
  *reinterpret_cast<short4v*>(wt + (size_t)(bn + r) * K + bk + c) = o;
}

// ---------------- mod = silu(vec) @ mod_w  (split-K GEMV) ----------------
__global__ __launch_bounds__(256) void k_modpart(const float* __restrict__ vec,
                                                 const float* __restrict__ mod_w,
                                                 float* __restrict__ partial) {
  __shared__ float sv[128];
  int t = threadIdx.x;
  int nb = blockIdx.x * 256;
  int kb = blockIdx.y * 128;
  if (t < 128) { float z = vec[kb + t]; sv[t] = z / (1.0f + expf(-z)); }
  __syncthreads();
  const float* wp = mod_w + (size_t)kb * NQKV + nb + t;
  float acc = 0.0f;
#pragma unroll 8
  for (int k = 0; k < 128; k++) acc += sv[k] * wp[(size_t)k * NQKV];
  partial[(size_t)blockIdx.y * NQKV + nb + t] = acc;
}

__global__ __launch_bounds__(256) void k_modred(const float* __restrict__ partial,
                                                const float* __restrict__ mod_b,
                                                float* __restrict__ modv) {
  int n = blockIdx.x * 256 + threadIdx.x;
  float acc = mod_b[n];
#pragma unroll
  for (int ky = 0; ky < 24; ky++) acc += partial[(size_t)ky * NQKV + n];
  modv[n] = acc;
}

// ---------------- LayerNorm + (1+scale)*xn + shift -> bf16 ----------------
__global__ __launch_bounds__(256) void k_ln(const float* __restrict__ x,
                                            const float* __restrict__ modv,
                                            short* __restrict__ xmod) {
  int l = blockIdx.x, t = threadIdx.x;
  const float* xr = x + (size_t)l * DMODEL;
  const float4* xr4 = (const float4*)xr;
  float4 vbuf[3];
  float s = 0.f, ss = 0.f;
#pragma unroll
  for (int i = 0; i < 3; i++) {
    float4 v = xr4[t + i * 256];
    vbuf[i] = v;
    s += v.x + v.y + v.z + v.w;
    ss += v.x * v.x + v.y * v.y + v.z * v.z + v.w * v.w;
  }
#pragma unroll
  for (int m = 32; m >= 1; m >>= 1) { s += __shfl_xor(s, m); ss += __shfl_xor(ss, m); }
  __shared__ float red[8];
  __shared__ float stats[2];
  int wave = t >> 6;
  if ((t & 63) == 0) { red[wave] = s; red[4 + wave] = ss; }
  __syncthreads();
  if (t == 0) {
    float st = red[0] + red[1] + red[2] + red[3];
    float sst = red[4] + red[5] + red[6] + red[7];
    float mu = st / DMODEL;
    float var = sst / DMODEL - mu * mu;
    stats[0] = mu; stats[1] = rsqrtf(var + EPSV);
  }
  __syncthreads();
  float mu = stats[0], rr = stats[1];
#pragma unroll
  for (int i = 0; i < 3; i++) {
    float4 v = vbuf[i];
    int c = (t + i * 256) * 4;
    short4v o;
    o[0] = f2bf((1.f + modv[DMODEL + c + 0]) * ((v.x - mu) * rr) + modv[c + 0]);
    o[1] = f2bf((1.f + modv[DMODEL + c + 1]) * ((v.y - mu) * rr) + modv[c + 1]);
    o[2] = f2bf((1.f + modv[DMODEL + c + 2]) * ((v.z - mu) * rr) + modv[c + 2]);
    o[3] = f2bf((1.f + modv[DMODEL + c + 3]) * ((v.w - mu) * rr) + modv[c + 3]);
    *(short4v*)(xmod + (size_t)l * DMODEL + c) = o;
  }
}

// ---------------- 8-phase 256x256 GEMM machinery (T1+T2+T3/T4+T5) ----------------
// Quadrant order (mh,nh): (0,0)(0,1)(1,1)(1,0); LDS half-tile retirement:
// A0@ph1, B1@ph2, A1@ph3, B0@ph4 -> prefetch issue 1 half-tile/phase, 3 in flight.
#define G1_NT 48    // 3072 / 64
#define G1_NITER 24 // 2 K-tiles per iteration
#define G2_KC 3840  // K per split-K chunk (15360 / 4)
#define G2_NT 60    // 3840 / 64
#define G2_NITER 30

__device__ __forceinline__ void ldA4(short8 af[4][2], const short* ldsA, int rbase,
                                     int lrow, const int* kOff) {
#pragma unroll
  for (int m = 0; m < 4; m++)
#pragma unroll
    for (int ks = 0; ks < 2; ks++)
      af[m][ks] = *(const short8*)&ldsA[(rbase + m * 16 + lrow) * 64 + kOff[ks]];
}

__device__ __forceinline__ void ldB2(short8 bfr[2][2], const short* ldsB, int rbase,
                                     int lrow, const int* kOff) {
#pragma unroll
  for (int n = 0; n < 2; n++)
#pragma unroll
    for (int ks = 0; ks < 2; ks++)
      bfr[n][ks] = *(const short8*)&ldsB[(rbase + n * 16 + lrow) * 64 + kOff[ks]];
}

// A half-tile (mh): rows mh*64 + {0..63} and 128+mh*64 + {0..63}; 16 chunks of 8 rows.
__device__ __forceinline__ void stage_halfA(short* ldsT, const short* G, int rowbase,
                                            int tauB, int half, int wid, int srow, int sk,
                                            size_t strideB) {
#pragma unroll
  for (int c = 0; c < 2; c++) {
    int j = c * 8 + wid;
    int row0 = ((j >> 3) << 7) + half * 64 + ((j & 7) << 3);
    const char* src = (const char*)G +
                      (size_t)(rowbase + row0 + srow) * strideB + tauB + sk;
    async_ld16(ldsT + row0 * 64, src);
  }
}

// B half-tile (nh): rows wq*64 + nh*32 + {0..31} for wq=0..3; 16 chunks of 8 rows.
__device__ __forceinline__ void stage_halfB(short* ldsT, const short* G, int rowbase,
                                            int tauB, int half, int wid, int srow, int sk,
                                            size_t strideB) {
#pragma unroll
  for (int c = 0; c < 2; c++) {
    int j = c * 8 + wid;
    int row0 = ((j >> 2) << 6) + half * 32 + ((j & 3) << 3);
    const char* src = (const char*)G +
                      (size_t)(rowbase + row0 + srow) * strideB + tauB + sk;
    async_ld16(ldsT + row0 * 64, src);
  }
}

#define SYNC_MFMA(mh, nh, VM)                                                       \
  do {                                                                              \
    if (VM) asm volatile("s_waitcnt vmcnt(6)" ::: "memory");                        \
    __builtin_amdgcn_s_barrier();                                                   \
    asm volatile("s_waitcnt lgkmcnt(0)" ::: "memory");                              \
    __builtin_amdgcn_sched_barrier(0);                                              \
    __builtin_amdgcn_s_setprio(1);                                                  \
    _Pragma("unroll") for (int m_ = 0; m_ < 4; m_++)                                \
      _Pragma("unroll") for (int n_ = 0; n_ < 2; n_++)                              \
        _Pragma("unroll") for (int k_ = 0; k_ < 2; k_++)                            \
          acc[(mh) * 4 + m_][(nh) * 2 + n_] =                                       \
              __builtin_amdgcn_mfma_f32_16x16x32_bf16(                              \
                  af[m_][k_], bfr[n_][k_], acc[(mh) * 4 + m_][(nh) * 2 + n_], 0, 0, 0); \
    __builtin_amdgcn_s_setprio(0);                                                  \
    __builtin_amdgcn_s_barrier();                                                   \
  } while (0)

#define G1_TB(tt) ((((tt) < G1_NT) ? (tt) : (G1_NT - 1)) * 128)
#define G2_TB(tt) ((((tt) < G2_NT) ? (tt) : (G2_NT - 1)) * 128)

__global__ __launch_bounds__(512, 2) void k_gemm1_8p(const short* __restrict__ A,
                                                     const short* __restrict__ Bt,
                                                     const float* __restrict__ bias,
                                                     float* __restrict__ qraw,
                                                     float* __restrict__ kraw,
                                                     short* __restrict__ vt,
                                                     short* __restrict__ a2) {
  __shared__ __align__(16) short lds[2][2][256 * 64];  // [buf][A/B][row*64] = 128 KiB
  int t = threadIdx.x;
  int wid = t >> 6, lane = t & 63;
  // T1: XCD-chunked bijective swizzle (672 % 8 == 0, 84 blocks/XCD chunk)
  int bid = blockIdx.x;
  int swzb = (bid & 7) * 84 + (bid >> 3);
  int bm = (swzb & 7) << 8;   // 8 M-tiles
  int bn = (swzb >> 3) << 8;  // 84 N-tiles
  int wm_ = (wid >> 2) << 7;  // 0 / 128
  int wn_ = (wid & 3) << 6;   // 0 / 64 / 128 / 192
  int lrow = lane & 15;
  int swzx = (lane & 7) << 4;  // byte XOR for frag reads (row&7 == lane&7 at all frag rows)
  int kOff[2];
#pragma unroll
  for (int ks = 0; ks < 2; ks++) kOff[ks] = ((ks * 64 + (lane >> 4) * 16) ^ swzx) >> 1;
  int srow = lane >> 3;                         // staging row within 8-row wave chunk
  int sk = ((lane & 7) * 16) ^ (srow << 4);     // pre-swizzled global chunk offset
  const size_t strA = (size_t)(DMODEL * 2);

  short* A0p = &lds[0][0][0];
  short* B0p = &lds[0][1][0];
  short* A1p = &lds[1][0][0];
  short* B1p = &lds[1][1][0];

  f32x4 zero = {0.f, 0.f, 0.f, 0.f};
  f32x4 acc[8][4];
#pragma unroll
  for (int i = 0; i < 8; i++)
#pragma unroll
    for (int j = 0; j < 4; j++) acc[i][j] = zero;
  short8 af[4][2], bfr[2][2];

  // prologue: tile0 (4 half-tiles) + tile1 {A0, B1, A1}; vmcnt(6) ensures tile0 resident
  stage_halfA(A0p, A, bm, 0, 0, wid, srow, sk, strA);
  stage_halfA(A0p, A, bm, 0, 1, wid, srow, sk, strA);
  stage_halfB(B0p, Bt, bn, 0, 0, wid, srow, sk, strA);
  stage_halfB(B0p, Bt, bn, 0, 1, wid, srow, sk, strA);
  stage_halfA(A1p, A, bm, 128, 0, wid, srow, sk, strA);
  stage_halfB(B1p, Bt, bn, 128, 1, wid, srow, sk, strA);
  stage_halfA(A1p, A, bm, 128, 1, wid, srow, sk, strA);
  asm volatile("s_waitcnt vmcnt(6)" ::: "memory");
  __builtin_amdgcn_s_barrier();

#pragma unroll 1
  for (int it = 0; it < G1_NITER; ++it) {
    int T = it * 2;
    // ---- phases 1-4: compute tile T (buf0) ----
    ldA4(af, A0p, wm_, lrow, kOff);
    ldB2(bfr, B0p, wn_, lrow, kOff);
    stage_halfB(B1p, Bt, bn, G1_TB(T + 1), 0, wid, srow, sk, strA);
    SYNC_MFMA(0, 0, 0);
    ldB2(bfr, B0p, wn_ + 32, lrow, kOff);
    stage_halfA(A0p, A, bm, G1_TB(T + 2), 0, wid, srow, sk, strA);
    SYNC_MFMA(0, 1, 0);
    ldA4(af, A0p, wm_ + 64, lrow, kOff);
    stage_halfB(B0p, Bt, bn, G1_TB(T + 2), 1, wid, srow, sk, strA);
    SYNC_MFMA(1, 1, 0);
    ldB2(bfr, B0p, wn_, lrow, kOff);
    stage_halfA(A0p, A, bm, G1_TB(T + 2), 1, wid, srow, sk, strA);
    SYNC_MFMA(1, 0, 1);
    // ---- phases 5-8: compute tile T+1 (buf1) ----
    ldA4(af, A1p, wm_, lrow, kOff);
    ldB2(bfr, B1p, wn_, lrow, kOff);
    stage_halfB(B0p, Bt, bn, G1_TB(T + 2), 0, wid, srow, sk, strA);
    SYNC_MFMA(0, 0, 0);
    ldB2(bfr, B1p, wn_ + 32, lrow, kOff);
    stage_halfA(A1p, A, bm, G1_TB(T + 3), 0, wid, srow, sk, strA);
    SYNC_MFMA(0, 1, 0);
    ldA4(af, A1p, wm_ + 64, lrow, kOff);
    stage_halfB(B1p, Bt, bn, G1_TB(T + 3), 1, wid, srow, sk, strA);
    SYNC_MFMA(1, 1, 0);
    ldB2(bfr, B1p, wn_, lrow, kOff);
    stage_halfA(A1p, A, bm, G1_TB(T + 3), 1, wid, srow, sk, strA);
    SYNC_MFMA(1, 0, 1);
  }

  // epilogue: per-wave 128x64 C region; C/D layout col=lane&15, row=(lane>>4)*4+r
  int r0 = bm + wm_ + ((lane >> 4) << 2);
  int c0 = bn + wn_ + lrow;
#pragma unroll
  for (int an = 0; an < 4; an++) {
    int col = c0 + an * 16;
    float bb = bias[col];
#pragma unroll
    for (int am = 0; am < 8; am++) {
#pragma unroll
      for (int r = 0; r < 4; r++) {
        float v = acc[am][an][r] + bb;
        int row = r0 + am * 16 + r;
        if (col < NQKV) {
          int s = col / DMODEL;
          int rem = col - s * DMODEL;
          int hh = rem >> 7, d = rem & 127;
          if (s == 0)      qraw[((size_t)hh * LQ + row) * DHEADC + d] = v;
          else if (s == 1) kraw[((size_t)hh * LQ + row) * DHEADC + d] = v;
          else             vt[((size_t)hh * DHEADC + d) * LQ + row] = f2bf(v);
        } else {
          a2[(size_t)row * KIN2 + DMODEL + (col - NQKV)] = f2bf(geluf(v));
        }
      }
    }
  }
}

// ---------------- GEMM2 split-K (S=4): a2(2048x15360) @ W2t(3072x15360)^T ----------------
// Same 8-phase schedule; each block does a 256x256 tile over one K-chunk of 3840,
// writes fp32 partial (no bias). 96 tiles x 4 chunks = 384 blocks.
__global__ __launch_bounds__(512, 2) void k_gemm2_8p(const short* __restrict__ A,
                                                     const short* __restrict__ Bt,
                                                     float* __restrict__ part) {
  __shared__ __align__(16) short lds[2][2][256 * 64];  // 128 KiB
  int t = threadIdx.x;
  int wid = t >> 6, lane = t & 63;
  // T1: XCD-chunked bijective swizzle (384 % 8 == 0, 48 per XCD chunk)
  int bid = blockIdx.x;
  int swzb = (bid & 7) * 48 + (bid >> 3);
  int bmIdx = swzb & 7;          // 8 M-tiles
  int g = swzb >> 3;             // 0..47 : (chunk, n-tile) group
  int bnIdx = g % 12;            // 12 N-tiles
  int s = g / 12;                // 4 K-chunks
  int bm = bmIdx << 8;
  int bn = bnIdx << 8;
  const short* Ab = A + (size_t)s * G2_KC;
  const short* Bb = Bt + (size_t)s * G2_KC;
  float* Pb = part + (size_t)s * LQ * DMODEL;
  int wm_ = (wid >> 2) << 7;
  int wn_ = (wid & 3) << 6;
  int lrow = lane & 15;
  int swzx = (lane & 7) << 4;
  int kOff[2];
#pragma unroll
  for (int ks = 0; ks < 2; ks++) kOff[ks] = ((ks * 64 + (lane >> 4) * 16) ^ swzx) >> 1;
  int srow = lane >> 3;
  int sk = ((lane & 7) * 16) ^ (srow << 4);
  const size_t strA = (size_t)(KIN2 * 2);

  short* A0p = &lds[0][0][0];
  short* B0p = &lds[0][1][0];
  short* A1p = &lds[1][0][0];
  short* B1p = &lds[1][1][0];

  f32x4 zero = {0.f, 0.f, 0.f, 0.f};
  f32x4 acc[8][4];
#pragma unroll
  for (int i = 0; i < 8; i++)
#pragma unroll
    for (int j = 0; j < 4; j++) acc[i][j] = zero;
  short8 af[4][2], bfr[2][2];

  stage_halfA(A0p, Ab, bm, 0, 0, wid, srow, sk, strA);
  stage_halfA(A0p, Ab, bm, 0, 1, wid, srow, sk, strA);
  stage_halfB(B0p, Bb, bn, 0, 0, wid, srow, sk, strA);
  stage_halfB(B0p, Bb, bn, 0, 1, wid, srow, sk, strA);
  stage_halfA(A1p, Ab, bm, 128, 0, wid, srow, sk, strA);
  stage_halfB(B1p, Bb, bn, 128, 1, wid, srow, sk, strA);
  stage_halfA(A1p, Ab, bm, 128, 1, wid, srow, sk, strA);
  asm volatile("s_waitcnt vmcnt(6)" ::: "memory");
  __builtin_amdgcn_s_barrier();

#pragma unroll 1
  for (int it = 0; it < G2_NITER; ++it) {
    int T = it * 2;
    ldA4(af, A0p, wm_, lrow, kOff);
    ldB2(bfr, B0p, wn_, lrow, kOff);
    stage_halfB(B1p, Bb, bn, G2_TB(T + 1), 0, wid, srow, sk, strA);
    SYNC_MFMA(0, 0, 0);
    ldB2(bfr, B0p, wn_ + 32, lrow, kOff);
    stage_halfA(A0p, Ab, bm, G2_TB(T + 2), 0, wid, srow, sk, strA);
    SYNC_MFMA(0, 1, 0);
    ldA4(af, A0p, wm_ + 64, lrow, kOff);
    stage_halfB(B0p, Bb, bn, G2_TB(T + 2), 1, wid, srow, sk, strA);
    SYNC_MFMA(1, 1, 0);
    ldB2(bfr, B0p, wn_, lrow, kOff);
    stage_halfA(A0p, Ab, bm, G2_TB(T + 2), 1, wid, srow, sk, strA);
    SYNC_MFMA(1, 0, 1);
    ldA4(af, A1p, wm_, lrow, kOff);
    ldB2(bfr, B1p, wn_, lrow, kOff);
    stage_halfB(B0p, Bb, bn, G2_TB(T + 2), 0, wid, srow, sk, strA);
    SYNC_MFMA(0, 0, 0);
    ldB2(bfr, B1p, wn_ + 32, lrow, kOff);
    stage_halfA(A1p, Ab, bm, G2_TB(T + 3), 0, wid, srow, sk, strA);
    SYNC_MFMA(0, 1, 0);
    ldA4(af, A1p, wm_ + 64, lrow, kOff);
    stage_halfB(B1p, Bb, bn, G2_TB(T + 3), 1, wid, srow, sk, strA);
    SYNC_MFMA(1, 1, 0);
    ldB2(bfr, B1p, wn_, lrow, kOff);
    stage_halfA(A1p, Ab, bm, G2_TB(T + 3), 1, wid, srow, sk, strA);
    SYNC_MFMA(1, 0, 1);
  }

  // epilogue: fp32 partial write (no bias), region rows bm..bm+255 x cols bn..bn+255
  int r0 = bm + wm_ + ((lane >> 4) << 2);
  int c0 = bn + wn_ + lrow;
#pragma unroll
  for (int an = 0; an < 4; an++) {
    int col = c0 + an * 16;
#pragma unroll
    for (int am = 0; am < 8; am++) {
#pragma unroll
      for (int r = 0; r < 4; r++) {
        int row = r0 + am * 16 + r;
        Pb[(size_t)row * DMODEL + col] = acc[am][an][r];
      }
    }
  }
}

// ---------------- reduce 4 partials + bias + gate + residual ----------------
__global__ __launch_bounds__(256) void k_g2red(const float* __restrict__ part,
                                               const float* __restrict__ bias,
                                               const float* __restrict__ x,
                                               const float* __restrict__ gate,
                                               float* __restrict__ out) {
  int idx = blockIdx.x * 256 + threadIdx.x;  // float4 index over 2048x3072
  int c4 = idx % (DMODEL / 4);
  const float4* p4 = (const float4*)part;
  const size_t st4 = (size_t)LQ * DMODEL / 4;
  float4 s0 = p4[idx];
  float4 s1 = p4[idx + st4];
  float4 s2 = p4[idx + 2 * st4];
  float4 s3 = p4[idx + 3 * st4];
  float4 b4 = ((const float4*)bias)[c4];
  float4 g4 = ((const float4*)gate)[c4];
  float4 x4 = ((const float4*)x)[idx];
  float4 o;
  o.x = x4.x + g4.x * (b4.x + s0.x + s1.x + s2.x + s3.x);
  o.y = x4.y + g4.y * (b4.y + s0.y + s1.y + s2.y + s3.y);
  o.z = x4.z + g4.z * (b4.z + s0.z + s1.z + s2.z + s3.z);
  o.w = x4.w + g4.w * (b4.w + s0.w + s1.w + s2.w + s3.w);
  ((float4*)out)[idx] = o;
}

// ---------------- RMSnorm + RoPE for q,k -> bf16 [h][l][d] ----------------
__global__ __launch_bounds__(256) void k_qkprep(const float* __restrict__ qraw,
                                                const float* __restrict__ kraw,
                                                const float* __restrict__ pe,
                                                const float* __restrict__ q_scale,
                                                const float* __restrict__ k_scale,
                                                short* __restrict__ qn,
                                                short* __restrict__ kn) {
  int wave = threadIdx.x >> 6, lane = threadIdx.x & 63;
  int l = blockIdx.x * 4 + wave;
  int h = blockIdx.y;
  int isK = blockIdx.z;
  const float* src = (isK ? kraw : qraw) + ((size_t)h * LQ + l) * DHEADC;
  const float* sc  = isK ? k_scale : q_scale;
  short* dst = (isK ? kn : qn) + ((size_t)h * LQ + l) * DHEADC;
  float2 tv = *(const float2*)(src + lane * 2);
  float ssq = tv.x * tv.x + tv.y * tv.y;
#pragma unroll
  for (int m = 1; m < 64; m <<= 1) ssq += __shfl_xor(ssq, m);
  float rr = rsqrtf(ssq * (1.0f / 128.0f) + EPSV);
  float t0 = tv.x * rr * sc[lane * 2];
  float t1 = tv.y * rr * sc[lane * 2 + 1];
  float4 p4 = *(const float4*)(pe + ((size_t)l * 64 + lane) * 4);
  float o0 = p4.x * t0 + p4.y * t1;
  float o1 = p4.z * t0 + p4.w * t1;
  if (!isK) { o0 *= 0.08838834764831845f; o1 *= 0.08838834764831845f; }  // 1/sqrt(128)
  dst[lane * 2] = f2bf(o0);
  dst[lane * 2 + 1] = f2bf(o1);
}

// ---------------- Flash attention: block = (head, 128 q rows) ----------------
__global__ __launch_bounds__(256) void k_flash(const short* __restrict__ qn,
                                               const short* __restrict__ kn,
                                               const short* __restrict__ vt,
                                               short* __restrict__ a2) {
  __shared__ short Qs[128][136];
  __shared__ short Ks[32][136];
  __shared__ short Vs[128][40];
  __shared__ short Ps[4][32][40];
  int t = threadIdx.x;
  int qb = blockIdx.x * 128, h = blockIdx.y;
  int wave = t >> 6, lane = t & 63;
  int lrow = lane & 15, lko = (lane >> 4) * 8;
  int wm = wave * 32;
  const short* qbase = qn + ((size_t)h * LQ + qb) * DHEADC;
#pragma unroll
  for (int i = 0; i < 8; i++) {
    int idx = i * 256 + t;
    int row = idx >> 4, c = (idx & 15) * 8;
    *(short8*)&Qs[row][c] = *(const short8*)(qbase + (size_t)row * DHEADC + c);
  }
  f32x4 zero = {0.f, 0.f, 0.f, 0.f};
  f32x4 oacc[2][8];
#pragma unroll
  for (int i = 0; i < 2; i++)
#pragma unroll
    for (int j = 0; j < 8; j++) oacc[i][j] = zero;
  float mI[2][4], lI[2][4];
#pragma unroll
  for (int i = 0; i < 2; i++)
#pragma unroll
    for (int r = 0; r < 4; r++) { mI[i][r] = -1e30f; lI[i][r] = 0.f; }
  __syncthreads();
  for (int kt = 0; kt < 64; kt++) {
    int krow0 = kt * 32;
#pragma unroll
    for (int i = 0; i < 2; i++) {
      int idx = i * 256 + t;
      int row = idx >> 4, c = (idx & 15) * 8;
      *(short8*)&Ks[row][c] = *(const short8*)(kn + ((size_t)h * LQ + krow0 + row) * DHEADC + c);
    }
#pragma unroll
    for (int i = 0; i < 2; i++) {
      int idx = i * 256 + t;
      int d = idx >> 2, c = (idx & 3) * 8;
      *(short8*)&Vs[d][c] = *(const short8*)(vt + ((size_t)h * DHEADC + d) * LQ + krow0 + c);
    }
    __syncthreads();
    f32x4 sacc[2][2];
#pragma unroll
    for (int i = 0; i < 2; i++)
#pragma unroll
      for (int j = 0; j < 2; j++) sacc[i][j] = zero;
#pragma unroll
    for (int kk = 0; kk < 4; kk++) {
      short8 qa[2], kb[2];
#pragma unroll
      for (int i = 0; i < 2; i++) qa[i] = *(const short8*)&Qs[wm + i * 16 + lrow][kk * 32 + lko];
#pragma unroll
      for (int j = 0; j < 2; j++) kb[j] = *(const short8*)&Ks[j * 16 + lrow][kk * 32 + lko];
#pragma unroll
      for (int i = 0; i < 2; i++)
#pragma unroll
        for (int j = 0; j < 2; j++)
          sacc[i][j] = __builtin_amdgcn_mfma_f32_16x16x32_bf16(qa[i], kb[j], sacc[i][j], 0, 0, 0);
    }
    // online softmax (rows live in (lane>>4, reg); reduce across lane&15)
#pragma unroll
    for (int i = 0; i < 2; i++) {
      float al[4];
#pragma unroll
      for (int r = 0; r < 4; r++) {
        float mx = fmaxf(sacc[i][0][r], sacc[i][1][r]);
#pragma unroll
        for (int m = 1; m < 16; m <<= 1) mx = fmaxf(mx, __shfl_xor(mx, m));
        float mnew = fmaxf(mI[i][r], mx);
        float alpha = exp2f((mI[i][r] - mnew) * 1.4426950408889634f);
        float p0 = exp2f((sacc[i][0][r] - mnew) * 1.4426950408889634f);
        float p1 = exp2f((sacc[i][1][r] - mnew) * 1.4426950408889634f);
        sacc[i][0][r] = p0; sacc[i][1][r] = p1;
        float rs = p0 + p1;
#pragma unroll
        for (int m = 1; m < 16; m <<= 1) rs += __shfl_xor(rs, m);
        lI[i][r] = lI[i][r] * alpha + rs;
        mI[i][r] = mnew;
        al[r] = alpha;
      }
#pragma unroll
      for (int j = 0; j < 8; j++) {
        f32x4 o = oacc[i][j];
        o[0] *= al[0]; o[1] *= al[1]; o[2] *= al[2]; o[3] *= al[3];
        oacc[i][j] = o;
      }
      // P: C/D layout -> LDS (transpose to A-operand layout)
#pragma unroll
      for (int j = 0; j < 2; j++)
#pragma unroll
        for (int r = 0; r < 4; r++)
          Ps[wave][i * 16 + (lane >> 4) * 4 + r][j * 16 + lrow] = f2bf(sacc[i][j][r]);
    }
    short8 pa[2];
#pragma unroll
    for (int i = 0; i < 2; i++) pa[i] = *(const short8*)&Ps[wave][i * 16 + lrow][lko];
#pragma unroll
    for (int j = 0; j < 8; j++) {
      short8 vb = *(const short8*)&Vs[j * 16 + lrow][lko];
#pragma unroll
      for (int i = 0; i < 2; i++)
        oacc[i][j] = __builtin_amdgcn_mfma_f32_16x16x32_bf16(pa[i], vb, oacc[i][j], 0, 0, 0);
    }
    __syncthreads();
  }
#pragma unroll
  for (int i = 0; i < 2; i++) {
    float inv[4];
#pragma unroll
    for (int r = 0; r < 4; r++) inv[r] = 1.0f / lI[i][r];
#pragma unroll
    for (int j = 0; j < 8; j++) {
#pragma unroll
      for (int r = 0; r < 4; r++) {
        int row = qb + wm + i * 16 + (lane >> 4) * 4 + r;
        int col = h * DHEADC + j * 16 + lrow;
        a2[(size_t)row * KIN2 + col] = f2bf(oacc[i][j][r] * inv[r]);
      }
    }
  }
}

extern "C" void kernel_launch(void* const* d_in, const int* in_sizes, int n_in,
                              void* d_out, int out_size, void* d_ws, size_t ws_size,
                              hipStream_t stream) {
  (void)in_sizes; (void)n_in; (void)out_size; (void)ws_size;
  const float* x       = (const float*)d_in[0];
  const float* vec     = (const float*)d_in[1];
  const float* pe      = (const float*)d_in[2];
  const float* mod_w   = (const float*)d_in[3];
  const float* mod_b   = (const float*)d_in[4];
  const float* lin1_w  = (const float*)d_in[5];
  const float* lin1_b  = (const float*)d_in[6];
  const float* lin2_w  = (const float*)d_in[7];
  const float* lin2_b  = (const float*)d_in[8];
  const float* q_scale = (const float*)d_in[9];
  const float* k_scale = (const float*)d_in[10];
  float* out = (float*)d_out;

  char* base = (char*)d_ws;
  size_t off = 0;
  auto carve = [&](size_t bytes) -> void* {
    void* q = base + off;
    off += (bytes + 255) & ~(size_t)255;
    return q;
  };
  short* W1t  = (short*)carve((size_t)NOUT1 * DMODEL * 2);      // also W2t later
  short* xmod = (short*)carve((size_t)LQ * DMODEL * 2);
  float* qraw = (float*)carve((size_t)NHEADS * LQ * DHEADC * 4);
  float* kraw = (float*)carve((size_t)NHEADS * LQ * DHEADC * 4);
  short* qnb  = (short*)carve((size_t)NHEADS * LQ * DHEADC * 2);
  short* knb  = (short*)carve((size_t)NHEADS * LQ * DHEADC * 2);
  short* vtb  = (short*)carve((size_t)NHEADS * LQ * DHEADC * 2);
  short* a2   = (short*)carve((size_t)LQ * KIN2 * 2);
  float* modv = (float*)carve((size_t)NQKV * 4);
  float* part = (float*)carve((size_t)24 * NQKV * 4);
  // split-K partials (4 x 2048 x 3072 fp32 = 100,663,296 B) overlay the
  // xmod..vtb region (101,053,440 B), all dead by the time k_gemm2_8p runs.
  float* g2part = (float*)xmod;

  k_wconv<<<dim3(DMODEL / 32, NOUT1 / 32), 256, 0, stream>>>(lin1_w, W1t, DMODEL, NOUT1);
  k_modpart<<<dim3(NQKV / 256, 24), 256, 0, stream>>>(vec, mod_w, part);
  k_modred<<<NQKV / 256, 256, 0, stream>>>(part, mod_b, modv);
  k_ln<<<LQ, 256, 0, stream>>>(x, modv, xmod);
  k_gemm1_8p<<<dim3((LQ / 256) * (NOUT1 / 256)), 512, 0, stream>>>(xmod, W1t, lin1_b,
                                                                   qraw, kraw, vtb, a2);
  k_wconv<<<dim3(KIN2 / 32, DMODEL / 32), 256, 0, stream>>>(lin2_w, W1t, KIN2, DMODEL);
  k_qkprep<<<dim3(LQ / 4, NHEADS, 2), 256, 0, stream>>>(qraw, kraw, pe, q_scale, k_scale, qnb, knb);
  k_flash<<<dim3(LQ / 128, NHEADS), 256, 0, stream>>>(qnb, knb, vtb, a2);
  k_gemm2_8p<<<dim3(384), 512, 0, stream>>>(a2, W1t, g2part);
  k_g2red<<<dim3((LQ * DMODEL / 4) / 256), 256, 0, stream>>>(g2part, lin2_b, x,
                                                             modv + 2 * DMODEL, out);
}